// Round 11
// baseline (192.603 us; speedup 1.0000x reference)
//
#include <hip/hip_runtime.h>
#include <math.h>

#define NN 20000
#define KK 16
#define DD 256
#define VV 64
#define NT1 16
#define SAS 336  // A-tile row stride in bf16 elems (320 data + 16 pad)

typedef __attribute__((ext_vector_type(8))) __bf16 bf16x8;
typedef __attribute__((ext_vector_type(4))) float floatx4;
typedef __attribute__((ext_vector_type(2))) float floatx2;
typedef __attribute__((ext_vector_type(8))) unsigned short ushort8;
typedef __attribute__((ext_vector_type(4))) unsigned int uint4v;

__device__ __forceinline__ float4 ld4(const float* p) { return *reinterpret_cast<const float4*>(p); }

__device__ __forceinline__ unsigned short f2bf(float f) {
    union { float f; unsigned u; } v; v.f = f;
    unsigned r = v.u + 0x7FFFu + ((v.u >> 16) & 1u);
    return (unsigned short)(r >> 16);
}
__device__ __forceinline__ float bf2f(unsigned short u) {
    union { unsigned u; float f; } v; v.u = ((unsigned)u) << 16;
    return v.f;
}
__device__ __forceinline__ unsigned char f2q(float f) {  // fp8 e4m3, RTNE
    return (unsigned char)(__builtin_amdgcn_cvt_pk_fp8_f32(f, 0.f, 0u, false) & 0xFFu);
}
__device__ __forceinline__ float q2f(unsigned char q) {
    floatx2 r = __builtin_amdgcn_cvt_pk_f32_fp8((unsigned)q, false);
    return r.x;
}
__device__ __forceinline__ float ftanh(float v) {
    float e = __expf(2.f * v);
    return 1.f - 2.f * __builtin_amdgcn_rcpf(e + 1.f);
}

// Single setup launch:
//  blocks 0..191   : EW[layer][v][:] coalesced compute, scattered 2B store direct into U fragments
//  blocks 192..287 : W-copy fragments (kt<8) of U1/U23
//  blocks 288..5287: edge-histogram -> Hc, x -> bf16 (xh), kld := 0
__global__ __launch_bounds__(256) void ewhist(
    const int* __restrict__ ie, const float* __restrict__ im,
    const int* __restrict__ oe, const float* __restrict__ om,
    const float* __restrict__ x,
    const float* __restrict__ e1, const float* __restrict__ W1,
    const float* __restrict__ e2, const float* __restrict__ W2,
    const float* __restrict__ e3, const float* __restrict__ W3,
    unsigned short* __restrict__ U1, unsigned short* __restrict__ U23,
    unsigned short* __restrict__ Hc, unsigned short* __restrict__ xh,
    float* __restrict__ kld) {
    int blk = blockIdx.x, tid = threadIdx.x;
    if (blk < 192) {
        int layer = blk >> 6, v = blk & 63, d = tid;
        const float* emb = layer == 0 ? e1 : (layer == 1 ? e2 : e3);
        const float* W   = layer == 0 ? W1 : (layer == 1 ? W2 : W3);
        float acc = 0.f;
        #pragma unroll 8
        for (int j = 0; j < 256; ++j)
            acc += emb[v * DD + j] * W[(size_t)(256 + j) * DD + d];
        int kt = 8 + (v >> 5), quadp = (v & 31) >> 3, j = v & 7;
        if (layer == 0) {
            int g = (kt * 16 + (d >> 4)) * 64 + quadp * 16 + (d & 15);
            U1[(size_t)g * 8 + j] = f2bf(acc);
        } else {
            int n = (layer == 2) ? 256 + d : d;
            int g = (kt * 32 + (n >> 4)) * 64 + quadp * 16 + (n & 15);
            U23[(size_t)g * 8 + j] = f2bf(acc);
        }
    } else if (blk < 288) {
        int blkp = blk - 192;
        int u1path = blkp < 32;
        int NT = u1path ? 16 : 32;
        int g = (u1path ? blkp : blkp - 32) * 256 + tid;
        int lane = g & 63, ntk = g >> 6;
        int nt = ntk % NT, kt = ntk / NT;  // kt < 8 by construction
        int n = nt * 16 + (lane & 15);
        int kbase = kt * 32 + (lane >> 4) * 8;
        const float* W;
        if (u1path)       { W = W1; }
        else if (n < 256) { W = W2; }
        else              { W = W3; n -= 256; }
        unsigned short o8[8];
        #pragma unroll
        for (int j = 0; j < 8; ++j)
            o8[j] = f2bf(W[(size_t)(kbase + j) * DD + n]);
        unsigned short* U = u1path ? U1 : U23;
        *reinterpret_cast<uint4v*>(&U[(size_t)g * 8]) = *reinterpret_cast<uint4v*>(o8);
    } else {
        int pb = blk - 288;
        int w = tid >> 6, lane = tid & 63;
        int n = pb * 4 + w;
        int e = 0; float m = 0.f;
        if (lane < 16)      { e = ie[n * KK + lane];      m = im[n * KK + lane]; }
        else if (lane < 32) { e = oe[n * KK + lane - 16]; m = om[n * KK + lane - 16]; }
        float h = 0.f;
        #pragma unroll
        for (int j = 0; j < 32; ++j) {
            int ev = __shfl(e, j);
            float mv = __shfl(m, j);
            if (ev == lane) h += mv;
        }
        Hc[(size_t)n * 64 + lane] = f2bf(h);
        size_t base = (size_t)pb * 1024 + tid * 4;
        float4 v = ld4(x + base);
        ushort4 o; o.x = f2bf(v.x); o.y = f2bf(v.y); o.z = f2bf(v.z); o.w = f2bf(v.w);
        *reinterpret_cast<ushort4*>(xh + base) = o;
        if (pb == 0 && tid == 0) *kld = 0.f;
    }
}

// Fused pass 1: bf16 gather of x into LDS A-tile (16 loads hoisted into regs per row),
// then hidden = x + 2*b1 + [S1|H] @ U1. Writes f32 out + fp8 copy for the KLD path.
__global__ __launch_bounds__(256) void fmm1(const unsigned short* __restrict__ xh, const unsigned short* __restrict__ Hc,
                                            const int* __restrict__ ii, const float* __restrict__ im,
                                            const int* __restrict__ oi, const float* __restrict__ om,
                                            const unsigned short* __restrict__ U, const float* __restrict__ b,
                                            float* __restrict__ out, unsigned char* __restrict__ h8) {
    __shared__ unsigned short sA[16 * SAS];
    __shared__ int sidx[16][32];
    __shared__ float smsk[16][32];
    int n0 = blockIdx.x * 16;
    int tid = threadIdx.x;
    for (int q = tid; q < 512; q += 256) {
        int r = q >> 5, j = q & 31;
        int n = n0 + r;
        sidx[r][j] = (j < 16) ? ii[n * KK + j] : oi[n * KK + j - 16];
        smsk[r][j] = (j < 16) ? im[n * KK + j] : om[n * KK + j - 16];
    }
    if (tid < 128) {  // stage H cols [256,320)
        int r = tid >> 3, k8 = tid & 7;
        *reinterpret_cast<uint4v*>(&sA[r * SAS + 256 + k8 * 8]) =
            *reinterpret_cast<const uint4v*>(&Hc[(size_t)(n0 + r) * 64 + k8 * 8]);
    }
    __syncthreads();
    int lane = tid & 63, w = tid >> 6;
    int half = lane >> 5, c = (lane & 31) * 8;
    #pragma unroll
    for (int rr = 0; rr < 4; ++rr) {
        int row = w * 4 + rr;
        ushort8 u[16];
        #pragma unroll
        for (int j = 0; j < 16; ++j)
            u[j] = *reinterpret_cast<const ushort8*>(xh + (size_t)sidx[row][j * 2 + half] * DD + c);
        float acc[8] = {0.f, 0.f, 0.f, 0.f, 0.f, 0.f, 0.f, 0.f};
        #pragma unroll
        for (int j = 0; j < 16; ++j) {
            float m = smsk[row][j * 2 + half];
            #pragma unroll
            for (int z = 0; z < 8; ++z) acc[z] += m * bf2f(u[j][z]);
        }
        #pragma unroll
        for (int z = 0; z < 8; ++z) acc[z] += __shfl_xor(acc[z], 32);
        if (half == 0) {
            unsigned short o8[8];
            #pragma unroll
            for (int z = 0; z < 8; ++z) o8[z] = f2bf(acc[z]);
            *reinterpret_cast<uint4v*>(&sA[row * SAS + c]) = *reinterpret_cast<uint4v*>(o8);
        }
    }
    __syncthreads();
    int lr = lane & 15, quad = lane >> 4;
    float xp[4][4], bb[4];
    #pragma unroll
    for (int t = 0; t < 4; ++t) {
        int col = (w * 4 + t) * 16 + lr;
        bb[t] = 2.f * b[col];
        #pragma unroll
        for (int r = 0; r < 4; ++r)
            xp[t][r] = bf2f(xh[(size_t)(n0 + quad * 4 + r) * DD + col]);
    }
    floatx4 z = {0.f, 0.f, 0.f, 0.f};
    floatx4 acc[4] = {z, z, z, z};
    for (int kt = 0; kt < 10; ++kt) {
        bf16x8 a = *reinterpret_cast<const bf16x8*>(&sA[lr * SAS + kt * 32 + quad * 8]);
        #pragma unroll
        for (int t = 0; t < 4; ++t) {
            bf16x8 bf = *reinterpret_cast<const bf16x8*>(&U[(size_t)((kt * NT1 + w * 4 + t) * 64 + lane) * 8]);
            acc[t] = __builtin_amdgcn_mfma_f32_16x16x32_bf16(a, bf, acc[t], 0, 0, 0);
        }
    }
    #pragma unroll
    for (int t = 0; t < 4; ++t) {
        int col = (w * 4 + t) * 16 + lr;
        #pragma unroll
        for (int r = 0; r < 4; ++r) {
            size_t o = (size_t)(n0 + quad * 4 + r) * DD + col;
            float v = xp[t][r] + bb[t] + acc[t][r];
            out[o] = v;
            h8[o] = f2q(v);
        }
    }
}

// Fused pass 2: fp8 gather of hidden, ROW-PAIRED (16 loads in flight), into bf16 LDS
// A-tile, then BOTH mu and logvar bf16 matmuls + fast tanh + KLD atomic.
__global__ __launch_bounds__(256) void fmm23(const unsigned char* __restrict__ h8, const unsigned short* __restrict__ Hc,
                                             const int* __restrict__ ii, const float* __restrict__ im,
                                             const int* __restrict__ oi, const float* __restrict__ om,
                                             const unsigned short* __restrict__ U, const float* __restrict__ b2,
                                             const float* __restrict__ b3, float* __restrict__ kld) {
    __shared__ unsigned short sA[16 * SAS];
    __shared__ int sidx[16][32];
    __shared__ float smsk[16][32];
    __shared__ float red[4];
    int n0 = blockIdx.x * 16;
    int tid = threadIdx.x;
    for (int q = tid; q < 512; q += 256) {
        int r = q >> 5, j = q & 31;
        int n = n0 + r;
        sidx[r][j] = (j < 16) ? ii[n * KK + j] : oi[n * KK + j - 16];
        smsk[r][j] = (j < 16) ? im[n * KK + j] : om[n * KK + j - 16];
    }
    if (tid < 128) {
        int r = tid >> 3, k8 = tid & 7;
        *reinterpret_cast<uint4v*>(&sA[r * SAS + 256 + k8 * 8]) =
            *reinterpret_cast<const uint4v*>(&Hc[(size_t)(n0 + r) * 64 + k8 * 8]);
    }
    __syncthreads();
    int lane = tid & 63, w = tid >> 6;
    int g = lane >> 4, cl = lane & 15;
    #pragma unroll
    for (int pr = 0; pr < 2; ++pr) {
        int rowA = w * 4 + pr * 2, rowB = rowA + 1;
        uint4v ua[8], ub[8];
        #pragma unroll
        for (int j = 0; j < 8; ++j) {
            ua[j] = *reinterpret_cast<const uint4v*>(h8 + (size_t)sidx[rowA][g * 8 + j] * DD + cl * 16);
            ub[j] = *reinterpret_cast<const uint4v*>(h8 + (size_t)sidx[rowB][g * 8 + j] * DD + cl * 16);
        }
        float accA[16], accB[16];
        #pragma unroll
        for (int z = 0; z < 16; ++z) { accA[z] = 0.f; accB[z] = 0.f; }
        #pragma unroll
        for (int j = 0; j < 8; ++j) {
            float ma = smsk[rowA][g * 8 + j];
            float mb = smsk[rowB][g * 8 + j];
            #pragma unroll
            for (int d = 0; d < 4; ++d) {
                floatx2 a01 = __builtin_amdgcn_cvt_pk_f32_fp8(ua[j][d], false);
                floatx2 a23 = __builtin_amdgcn_cvt_pk_f32_fp8(ua[j][d], true);
                accA[d * 4 + 0] += ma * a01.x; accA[d * 4 + 1] += ma * a01.y;
                accA[d * 4 + 2] += ma * a23.x; accA[d * 4 + 3] += ma * a23.y;
                floatx2 b01 = __builtin_amdgcn_cvt_pk_f32_fp8(ub[j][d], false);
                floatx2 b23 = __builtin_amdgcn_cvt_pk_f32_fp8(ub[j][d], true);
                accB[d * 4 + 0] += mb * b01.x; accB[d * 4 + 1] += mb * b01.y;
                accB[d * 4 + 2] += mb * b23.x; accB[d * 4 + 3] += mb * b23.y;
            }
        }
        #pragma unroll
        for (int z = 0; z < 16; ++z) {
            accA[z] += __shfl_xor(accA[z], 16);
            accA[z] += __shfl_xor(accA[z], 32);
            accB[z] += __shfl_xor(accB[z], 16);
            accB[z] += __shfl_xor(accB[z], 32);
        }
        if (g == 0) {
            unsigned short oA[16], oB[16];
            #pragma unroll
            for (int z = 0; z < 16; ++z) { oA[z] = f2bf(accA[z]); oB[z] = f2bf(accB[z]); }
            uint4v* dA = reinterpret_cast<uint4v*>(&sA[rowA * SAS + cl * 16]);
            dA[0] = reinterpret_cast<uint4v*>(oA)[0];
            dA[1] = reinterpret_cast<uint4v*>(oA)[1];
            uint4v* dB = reinterpret_cast<uint4v*>(&sA[rowB * SAS + cl * 16]);
            dB[0] = reinterpret_cast<uint4v*>(oB)[0];
            dB[1] = reinterpret_cast<uint4v*>(oB)[1];
        }
    }
    __syncthreads();
    int lr = lane & 15, quad = lane >> 4;
    float hp[4][4], bm[4], bl[4];
    #pragma unroll
    for (int t = 0; t < 4; ++t) {
        int col = (w * 4 + t) * 16 + lr;
        bm[t] = 2.f * b2[col];
        bl[t] = 2.f * b3[col];
        #pragma unroll
        for (int r = 0; r < 4; ++r)
            hp[t][r] = q2f(h8[(size_t)(n0 + quad * 4 + r) * DD + col]);
    }
    floatx4 z = {0.f, 0.f, 0.f, 0.f};
    floatx4 am[4] = {z, z, z, z};
    floatx4 al[4] = {z, z, z, z};
    for (int kt = 0; kt < 10; ++kt) {
        bf16x8 a = *reinterpret_cast<const bf16x8*>(&sA[lr * SAS + kt * 32 + quad * 8]);
        #pragma unroll
        for (int t = 0; t < 4; ++t) {
            int nt = w * 4 + t;
            bf16x8 bmu = *reinterpret_cast<const bf16x8*>(&U[(size_t)((kt * 32 + nt) * 64 + lane) * 8]);
            bf16x8 blv = *reinterpret_cast<const bf16x8*>(&U[(size_t)((kt * 32 + 16 + nt) * 64 + lane) * 8]);
            am[t] = __builtin_amdgcn_mfma_f32_16x16x32_bf16(a, bmu, am[t], 0, 0, 0);
            al[t] = __builtin_amdgcn_mfma_f32_16x16x32_bf16(a, blv, al[t], 0, 0, 0);
        }
    }
    float kacc = 0.f;
    #pragma unroll
    for (int t = 0; t < 4; ++t) {
        #pragma unroll
        for (int r = 0; r < 4; ++r) {
            float h = hp[t][r];
            float tm = ftanh(h + bm[t] + am[t][r]);
            float tl = ftanh(h + bl[t] + al[t][r]);
            kacc += (1.f - tm * tm) + (2.f * tl - __expf(2.f * tl));
        }
    }
    #pragma unroll
    for (int off = 32; off > 0; off >>= 1) kacc += __shfl_xor(kacc, off);
    if (lane == 0) red[w] = kacc;
    __syncthreads();
    if (tid == 0)
        atomicAdd(kld, (red[0] + red[1] + red[2] + red[3]) * (-0.5f / ((float)NN * (float)NN)));
}

extern "C" void kernel_launch(void* const* d_in, const int* in_sizes, int n_in,
                              void* d_out, int out_size, void* d_ws, size_t ws_size,
                              hipStream_t stream) {
    const float* x  = (const float*)d_in[0];
    const int*   ii = (const int*)d_in[1];
    const int*   ie = (const int*)d_in[2];
    const float* im = (const float*)d_in[3];
    const int*   oi = (const int*)d_in[4];
    const int*   oe = (const int*)d_in[5];
    const float* om = (const float*)d_in[6];
    const float* e1 = (const float*)d_in[7];
    const float* W1 = (const float*)d_in[8];
    const float* b1 = (const float*)d_in[9];
    const float* e2 = (const float*)d_in[10];
    const float* W2 = (const float*)d_in[11];
    const float* b2 = (const float*)d_in[12];
    const float* e3 = (const float*)d_in[13];
    const float* W3 = (const float*)d_in[14];
    const float* b3 = (const float*)d_in[15];
    float* out = (float*)d_out;
    float* kld = out + (size_t)NN * DD;

    char* ws = (char*)d_ws;
    unsigned short* U1  = (unsigned short*)(ws);            // 163840 B
    unsigned short* U23 = (unsigned short*)(ws + 163840);   // 327680 B
    unsigned short* Hc  = (unsigned short*)(ws + 491520);   // 20000*64 bf16   (2.56 MB)
    unsigned short* xh  = (unsigned short*)(ws + 3051520);  // 20000*256 bf16  (10.24 MB)
    unsigned char*  h8  = (unsigned char*)(ws + 13291520);  // 20000*256 fp8   (5.12 MB)

    ewhist<<<288 + NN / 4, 256, 0, stream>>>(ie, im, oe, om, x, e1, W1, e2, W2, e3, W3,
                                             U1, U23, Hc, xh, kld);
    fmm1  <<<NN / 16, 256, 0, stream>>>(xh, Hc, ii, im, oi, om, U1, b1, out, h8);
    fmm23 <<<NN / 16, 256, 0, stream>>>(h8, Hc, ii, im, oi, om, U23, b2, b3, kld);
}